// Round 17
// baseline (93.500 us; speedup 1.0000x reference)
//
#include <hip/hip_runtime.h>
#include <hip/hip_bf16.h>

#define NHEADS 6
#define HD 32
#define CDIM 192
#define NTOK 64
#define NREL 225
#define PDIM 12
#define IMG 256
#define NWIN 2048
#define QSCALE 0.2550348686f      // 32^-0.5 * log2(e)
#define LOG2E 1.4426950408889634f

typedef __attribute__((ext_vector_type(8))) short v8s;
typedef __attribute__((ext_vector_type(4))) float v4f;

#define KS3 104  // ks row stride (ushort): 208B (2-way max on b128 reads)
#define VTS 72   // vt row stride: 144B

__device__ __forceinline__ unsigned pkbf(float x, float y) {
    __hip_bfloat162 h = __float22bfloat162_rn(make_float2(x, y));
    union { __hip_bfloat162 h; unsigned u; } c; c.h = h;
    return c.u;
}

__device__ __forceinline__ float ex2(float x) {
    float r; asm("v_exp_f32 %0, %1" : "=v"(r) : "v"(x)); return r;
}

__device__ __forceinline__ void ln_relu12(const float* x, const float* g,
                                          const float* be, float* y) {
    float m = 0.f;
#pragma unroll
    for (int i = 0; i < PDIM; ++i) m += x[i];
    m *= (1.f / PDIM);
    float v = 0.f;
#pragma unroll
    for (int i = 0; i < PDIM; ++i) { float d = x[i] - m; v += d * d; }
    v *= (1.f / PDIM);
    float inv = rsqrtf(v + 1e-5f);
#pragma unroll
    for (int i = 0; i < PDIM; ++i) {
        float t = (x[i] - m) * inv * g[i] + be[i];
        y[i] = t > 0.f ? t : 0.f;
    }
}

__global__ __launch_bounds__(256, 2) void win_attn_fused(
    const float* __restrict__ qkv,
    const float* __restrict__ wpj, const float* __restrict__ bp,
    const float* __restrict__ g1, const float* __restrict__ be1,
    const float* __restrict__ w1, const float* __restrict__ b1,
    const float* __restrict__ g2, const float* __restrict__ be2,
    const float* __restrict__ w2, const float* __restrict__ b2,
    const float* __restrict__ g3, const float* __restrict__ be3,
    const float* __restrict__ w3, const float* __restrict__ b3,
    float* __restrict__ out)
{
    __shared__ __align__(16) unsigned short ks[2][NTOK * KS3];
    __shared__ __align__(16) unsigned short vt[2][96 * VTS];
    __shared__ __align__(16) float pshf[NREL * 4];

    const int t = threadIdx.x;
    const int bid = blockIdx.x;
    const int hg    = bid >> 10;          // head-group 0/1 (heads hg*3..hg*3+2)
    const int wpair = bid & 1023;         // handles windows 2*wpair, 2*wpair+1
    const int hoff = hg * 96;

    const int lane = t & 63;
    const int rg   = t >> 6;
    const int lw = lane & 15;
    const int lg = lane >> 4;
    const int rowbase = rg * 16;

    const int win0 = wpair * 2, win1 = wpair * 2 + 1;
    const int bat0 = win0 >> 10, bh0 = (win0 >> 5) & 31, bw0 = win0 & 31;
    const int bat1 = win1 >> 10, bh1 = (win1 >> 5) & 31, bw1 = win1 & 31;

    const size_t PL = (size_t)2 * IMG * IMG * CDIM;
    const float* qpl0 = qkv + (size_t)bat0 * IMG * IMG * CDIM;
    const float* qpl1 = qkv + (size_t)bat1 * IMG * IMG * CDIM;

    auto pixoff = [&](int bh, int bw, int tok) -> size_t {
        return ((size_t)(bh * 8 + (tok >> 3)) * IMG + (bw * 8 + (tok & 7))) * CDIM;
    };

    // V staging decomposition (same lanes both tasks)
    const int tp = t & 31;
    const int vg = t >> 5;                // 0..7
    const int tok0 = 2 * tp;
    // k'(tok) = (tok>>5)*32 + ((tok>>2)&3)*8 + ((tok>>4)&1)*4 + (tok&3)
    const int k0 = ((tok0 >> 5) << 5) + (((tok0 >> 2) & 3) << 3)
                 + (((tok0 >> 4) & 1) << 2) + (tok0 & 3);

    // ================= T0 stage: load+convert+write immediately =================
#pragma unroll
    for (int pass = 0; pass < 6; ++pass) {
        int fidx = t + pass * 256;
        int pix = fidx / 24;
        int f   = fidx - pix * 24;
        float4 k4 = *(const float4*)(qpl0 + PL + pixoff(bh0, bw0, pix) + hoff + f * 4);
        uint2 kk; kk.x = pkbf(k4.x, k4.y); kk.y = pkbf(k4.z, k4.w);
        *(uint2*)&ks[0][pix * KS3 + f * 4] = kk;
    }
    {
        const size_t offa = pixoff(bh0, bw0, tok0) + hoff;
        const size_t offb = pixoff(bh0, bw0, tok0 + 1) + hoff;
#pragma unroll
        for (int i = 0; i < 3; ++i) {
            int f = vg + i * 8;
            float4 vA = *(const float4*)(qpl0 + 2 * PL + offa + f * 4);
            float4 vB = *(const float4*)(qpl0 + 2 * PL + offb + f * 4);
            int d0 = f * 4;
            *(unsigned*)&vt[0][(d0 + 0) * VTS + k0] = pkbf(vA.x, vB.x);
            *(unsigned*)&vt[0][(d0 + 1) * VTS + k0] = pkbf(vA.y, vB.y);
            *(unsigned*)&vt[0][(d0 + 2) * VTS + k0] = pkbf(vA.z, vB.z);
            *(unsigned*)&vt[0][(d0 + 3) * VTS + k0] = pkbf(vA.w, vB.w);
        }
    }

    // ---------- Q for both tasks (convert now; 24 VGPR) ----------
    v8s aq0[3], aq1[3];
    {
        const size_t qo0 = pixoff(bh0, bw0, rowbase + lw) + hoff;
        const size_t qo1 = pixoff(bh1, bw1, rowbase + lw) + hoff;
#pragma unroll
        for (int hi = 0; hi < 3; ++hi) {
            const float* qp = qpl0 + qo0 + hi * HD + lg * 8;
            float4 q0 = *(const float4*)qp;
            float4 q1 = *(const float4*)(qp + 4);
            union { v8s v; unsigned x[4]; } au;
            au.x[0] = pkbf(q0.x * QSCALE, q0.y * QSCALE);
            au.x[1] = pkbf(q0.z * QSCALE, q0.w * QSCALE);
            au.x[2] = pkbf(q1.x * QSCALE, q1.y * QSCALE);
            au.x[3] = pkbf(q1.z * QSCALE, q1.w * QSCALE);
            aq0[hi] = au.v;
            const float* qq = qpl1 + qo1 + hi * HD + lg * 8;
            float4 p0 = *(const float4*)qq;
            float4 p1 = *(const float4*)(qq + 4);
            au.x[0] = pkbf(p0.x * QSCALE, p0.y * QSCALE);
            au.x[1] = pkbf(p0.z * QSCALE, p0.w * QSCALE);
            au.x[2] = pkbf(p1.x * QSCALE, p1.y * QSCALE);
            au.x[3] = pkbf(p1.z * QSCALE, p1.w * QSCALE);
            aq1[hi] = au.v;
        }
    }

    // ================= T1 stage: ISSUE loads only (held in regs) =================
    float4 kreg[6];
#pragma unroll
    for (int pass = 0; pass < 6; ++pass) {
        int fidx = t + pass * 256;
        int pix = fidx / 24;
        int f   = fidx - pix * 24;
        kreg[pass] = *(const float4*)(qpl1 + PL + pixoff(bh1, bw1, pix) + hoff + f * 4);
    }
    float4 vA1[3], vB1[3];
    {
        const size_t offa = pixoff(bh1, bw1, tok0) + hoff;
        const size_t offb = pixoff(bh1, bw1, tok0 + 1) + hoff;
#pragma unroll
        for (int i = 0; i < 3; ++i) {
            int f = vg + i * 8;
            vA1[i] = *(const float4*)(qpl1 + 2 * PL + offa + f * 4);
            vB1[i] = *(const float4*)(qpl1 + 2 * PL + offb + f * 4);
        }
    }

    // ---------- fused MLP (hidden under staging; amortized over 2 windows) ----------
    if (t < NREL) {
        float x0 = (float)(t / 15 - 7);
        float x1 = (float)(t % 15 - 7);
        float h[PDIM], y[PDIM];
#pragma unroll
        for (int o = 0; o < PDIM; ++o)
            h[o] = x0 * wpj[o] + x1 * wpj[PDIM + o] + bp[o];
        ln_relu12(h, g1, be1, y);
#pragma unroll
        for (int o = 0; o < PDIM; ++o) {
            float a = b1[o];
#pragma unroll
            for (int i = 0; i < PDIM; ++i) a += y[i] * w1[i * PDIM + o];
            h[o] = a;
        }
        ln_relu12(h, g2, be2, y);
#pragma unroll
        for (int o = 0; o < PDIM; ++o) {
            float a = b2[o];
#pragma unroll
            for (int i = 0; i < PDIM; ++i) a += y[i] * w2[i * PDIM + o];
            h[o] = a;
        }
        ln_relu12(h, g3, be3, y);
#pragma unroll
        for (int hi = 0; hi < 3; ++hi) {
            int o = hg * 3 + hi;
            float a = b3[o];
#pragma unroll
            for (int i = 0; i < PDIM; ++i) a += y[i] * w3[i * NHEADS + o];
            pshf[t * 4 + hi] = a * LOG2E;
        }
    }
    __syncthreads();   // buf0 + pshf ready; T1 loads still in flight

    // ---------- compute + store one task ----------
    auto compute_store = [&](const unsigned short* ksb, const unsigned short* vtb,
                             const v8s* aq, int batt, int bhh, int bww) {
        v4f acc[3][4];
#pragma unroll
        for (int ct = 0; ct < 4; ++ct)
#pragma unroll
            for (int hi = 0; hi < 3; ++hi) {
                v4f z = {0.f, 0.f, 0.f, 0.f};
                v8s bfr = *(const v8s*)&ksb[(ct * 16 + lw) * KS3 + hi * HD + lg * 8];
                acc[hi][ct] = __builtin_amdgcn_mfma_f32_16x16x32_bf16(bfr, aq[hi], z, 0, 0, 0);
            }
        const int q = rowbase + lw;
        const int base2 = ((q >> 3) + 7) * 15 + (q & 7) + 7
                        - ((lg >> 1) * 15 + (lg & 1) * 4);
#pragma unroll
        for (int ct = 0; ct < 4; ++ct)
#pragma unroll
            for (int r = 0; r < 4; ++r) {
                int idx = base2 - ct * 30 - r;
                const float4 bb = *(const float4*)&pshf[idx * 4];
                acc[0][ct][r] = ex2(acc[0][ct][r] + bb.x);
                acc[1][ct][r] = ex2(acc[1][ct][r] + bb.y);
                acc[2][ct][r] = ex2(acc[2][ct][r] + bb.z);
            }
        unsigned pa[3][2][4];
#pragma unroll
        for (int hi = 0; hi < 3; ++hi) {
            float s = 0.f;
#pragma unroll
            for (int ct = 0; ct < 4; ++ct)
#pragma unroll
                for (int r = 0; r < 4; ++r) s += acc[hi][ct][r];
            s += __shfl_xor(s, 16);
            s += __shfl_xor(s, 32);
            float rv = __builtin_amdgcn_rcpf(s);
#pragma unroll
            for (int kt = 0; kt < 2; ++kt) {
                pa[hi][kt][0] = pkbf(acc[hi][2*kt][0] * rv, acc[hi][2*kt][1] * rv);
                pa[hi][kt][1] = pkbf(acc[hi][2*kt][2] * rv, acc[hi][2*kt][3] * rv);
                pa[hi][kt][2] = pkbf(acc[hi][2*kt+1][0] * rv, acc[hi][2*kt+1][1] * rv);
                pa[hi][kt][3] = pkbf(acc[hi][2*kt+1][2] * rv, acc[hi][2*kt+1][3] * rv);
            }
        }
        size_t ooff[4];
#pragma unroll
        for (int r = 0; r < 4; ++r) {
            int n = rowbase + lg * 4 + r;
            ooff[r] = ((size_t)(batt * IMG + bhh * 8 + (n >> 3)) * IMG
                       + (bww * 8 + (n & 7))) * CDIM;
        }
#pragma unroll
        for (int hi = 0; hi < 3; ++hi) {
            v4f acc2[2] = {};
#pragma unroll
            for (int kt = 0; kt < 2; ++kt) {
                v8s pav = *(const v8s*)&pa[hi][kt][0];
#pragma unroll
                for (int dt = 0; dt < 2; ++dt) {
                    v8s vb = *(const v8s*)&vtb[(hi * HD + dt * 16 + lw) * VTS
                                               + kt * 32 + lg * 8];
                    acc2[dt] = __builtin_amdgcn_mfma_f32_16x16x32_bf16(pav, vb, acc2[dt], 0, 0, 0);
                }
            }
            const int h = hg * 3 + hi;
#pragma unroll
            for (int dt = 0; dt < 2; ++dt)
#pragma unroll
                for (int r = 0; r < 4; ++r)
                    out[ooff[r] + h * HD + dt * 16 + lw] = acc2[dt][r];
        }
    };

    // T0 compute (T1 loads' HBM latency hides under this)
    compute_store(ks[0], vt[0], aq0, bat0, bh0, bw0);

    // ================= T1: convert + write (waitcnt lands here) =================
#pragma unroll
    for (int pass = 0; pass < 6; ++pass) {
        int fidx = t + pass * 256;
        int pix = fidx / 24;
        int f   = fidx - pix * 24;
        uint2 kk;
        kk.x = pkbf(kreg[pass].x, kreg[pass].y);
        kk.y = pkbf(kreg[pass].z, kreg[pass].w);
        *(uint2*)&ks[1][pix * KS3 + f * 4] = kk;
    }
#pragma unroll
    for (int i = 0; i < 3; ++i) {
        int d0 = (vg + i * 8) * 4;
        *(unsigned*)&vt[1][(d0 + 0) * VTS + k0] = pkbf(vA1[i].x, vB1[i].x);
        *(unsigned*)&vt[1][(d0 + 1) * VTS + k0] = pkbf(vA1[i].y, vB1[i].y);
        *(unsigned*)&vt[1][(d0 + 2) * VTS + k0] = pkbf(vA1[i].z, vB1[i].z);
        *(unsigned*)&vt[1][(d0 + 3) * VTS + k0] = pkbf(vA1[i].w, vB1[i].w);
    }
    __syncthreads();   // buf1 ready

    compute_store(ks[1], vt[1], aq1, bat1, bh1, bw1);
}

extern "C" void kernel_launch(void* const* d_in, const int* in_sizes, int n_in,
                              void* d_out, int out_size, void* d_ws, size_t ws_size,
                              hipStream_t stream) {
    const float* qkv = (const float*)d_in[0];
    win_attn_fused<<<NWIN, 256, 0, stream>>>(
        qkv,
        (const float*)d_in[1], (const float*)d_in[2],
        (const float*)d_in[3], (const float*)d_in[4],
        (const float*)d_in[5], (const float*)d_in[6],
        (const float*)d_in[7], (const float*)d_in[8],
        (const float*)d_in[9], (const float*)d_in[10],
        (const float*)d_in[11], (const float*)d_in[12],
        (const float*)d_in[13], (const float*)d_in[14],
        (float*)d_out);
}

// Round 18
// 84.454 us; speedup vs baseline: 1.1071x; 1.1071x over previous
//
#include <hip/hip_runtime.h>
#include <hip/hip_bf16.h>

#define NHEADS 6
#define HD 32
#define CDIM 192
#define NTOK 64
#define NREL 225
#define PDIM 12
#define IMG 256
#define NWIN 2048
#define QSCALE 0.2550348686f      // 32^-0.5 * log2(e)
#define LOG2E 1.4426950408889634f

typedef __attribute__((ext_vector_type(8))) short v8s;
typedef __attribute__((ext_vector_type(4))) float v4f;

#define KS3 104  // ks row stride (ushort): 96 ch + 8 pad = 208B
#define VTS 72   // vt row stride: 144B

__device__ __forceinline__ unsigned pkbf(float x, float y) {
    __hip_bfloat162 h = __float22bfloat162_rn(make_float2(x, y));
    union { __hip_bfloat162 h; unsigned u; } c; c.h = h;
    return c.u;
}

__device__ __forceinline__ float ex2(float x) {
    float r; asm("v_exp_f32 %0, %1" : "=v"(r) : "v"(x)); return r;
}

__device__ __forceinline__ void ln_relu12(const float* x, const float* g,
                                          const float* be, float* y) {
    float m = 0.f;
#pragma unroll
    for (int i = 0; i < PDIM; ++i) m += x[i];
    m *= (1.f / PDIM);
    float v = 0.f;
#pragma unroll
    for (int i = 0; i < PDIM; ++i) { float d = x[i] - m; v += d * d; }
    v *= (1.f / PDIM);
    float inv = rsqrtf(v + 1e-5f);
#pragma unroll
    for (int i = 0; i < PDIM; ++i) {
        float t = (x[i] - m) * inv * g[i] + be[i];
        y[i] = t > 0.f ? t : 0.f;
    }
}

__global__ __launch_bounds__(256, 4) void win_attn_fused(
    const float* __restrict__ qkv,
    const float* __restrict__ wp, const float* __restrict__ bp,
    const float* __restrict__ g1, const float* __restrict__ be1,
    const float* __restrict__ w1, const float* __restrict__ b1,
    const float* __restrict__ g2, const float* __restrict__ be2,
    const float* __restrict__ w2, const float* __restrict__ b2,
    const float* __restrict__ g3, const float* __restrict__ be3,
    const float* __restrict__ w3, const float* __restrict__ b3,
    float* __restrict__ out)
{
    __shared__ __align__(16) unsigned short ks[NTOK * KS3];  // K half (3 heads)
    __shared__ __align__(16) unsigned short vt[96 * VTS];    // V^T half, k' order
    __shared__ __align__(16) float pshf[NREL * 4];           // bias [idx][4]

    const int t = threadIdx.x;
    const int bid = blockIdx.x;
    const int win = bid >> 1;         // adjacent blocks share a window (pages)
    const int hg  = bid & 1;          // head-group: heads hg*3 .. hg*3+2
    const int b  = win >> 10;
    const int bh = (win >> 5) & 31;
    const int bw = win & 31;

    const int lane = t & 63;
    const int rg   = t >> 6;          // wave = row-group 0..3
    const int lw = lane & 15;
    const int lg = lane >> 4;
    const int rowbase = rg * 16;
    const int hoff = hg * 96;         // channel offset of this head-group

    const size_t PL = (size_t)2 * IMG * IMG * CDIM;
    const float* qplane = qkv + (size_t)b * IMG * IMG * CDIM;
    const float* kplane = qplane + PL;
    const float* vplane = kplane + PL;

    auto pixoff = [&](int tok) -> size_t {
        return ((size_t)(bh * 8 + (tok >> 3)) * IMG + (bw * 8 + (tok & 7))) * CDIM;
    };

    // ---------- K: issue 6 contiguous loads (384B runs per pixel-half) ----------
    float4 kreg[6];
    int kpix[6], kf[6];
#pragma unroll
    for (int pass = 0; pass < 6; ++pass) {
        int fidx = t + pass * 256;            // 0..1535
        int pix = fidx / 24;                  // 0..63
        int f   = fidx - pix * 24;            // 0..23 (float4 in 96-f32 half)
        kreg[pass] = *(const float4*)(kplane + pixoff(pix) + hoff + f * 4);
        kpix[pass] = pix; kf[pass] = f;
    }
    // convert + write immediately (short reg residency)
#pragma unroll
    for (int pass = 0; pass < 6; ++pass) {
        uint2 kk;
        kk.x = pkbf(kreg[pass].x, kreg[pass].y);
        kk.y = pkbf(kreg[pass].z, kreg[pass].w);
        *(uint2*)&ks[kpix[pass] * KS3 + kf[pass] * 4] = kk;
    }

    // ---------- V: k'-paired transpose (conflict-free b32 writes) ----------
    {
        const int tp = t & 31;                // token pair (2tp, 2tp+1)
        const int g  = t >> 5;                // 0..7
        const int tok0 = 2 * tp;
        // k'(tok) = (tok>>5)*32 + ((tok>>2)&3)*8 + ((tok>>4)&1)*4 + (tok&3)
        const int k0 = ((tok0 >> 5) << 5) + (((tok0 >> 2) & 3) << 3)
                     + (((tok0 >> 4) & 1) << 2) + (tok0 & 3);
        const size_t offa = pixoff(tok0) + hoff, offb = pixoff(tok0 + 1) + hoff;
#pragma unroll
        for (int i = 0; i < 3; ++i) {
            int f = g + i * 8;                // float4 slot 0..23
            float4 vA = *(const float4*)(vplane + offa + f * 4);
            float4 vB = *(const float4*)(vplane + offb + f * 4);
            int d0 = f * 4;
            *(unsigned*)&vt[(d0 + 0) * VTS + k0] = pkbf(vA.x, vB.x);
            *(unsigned*)&vt[(d0 + 1) * VTS + k0] = pkbf(vA.y, vB.y);
            *(unsigned*)&vt[(d0 + 2) * VTS + k0] = pkbf(vA.z, vB.z);
            *(unsigned*)&vt[(d0 + 3) * VTS + k0] = pkbf(vA.w, vB.w);
        }
    }

    // ---------- Q: this block's 3 heads, pre-scaled by SCALE*log2e ----------
    v8s aq[3];
    {
        const size_t qoff = pixoff(rowbase + lw) + hoff;
#pragma unroll
        for (int hi = 0; hi < 3; ++hi) {
            const float* qp = qplane + qoff + hi * HD + lg * 8;
            float4 q0 = *(const float4*)qp;
            float4 q1 = *(const float4*)(qp + 4);
            union { v8s v; unsigned x[4]; } au;
            au.x[0] = pkbf(q0.x * QSCALE, q0.y * QSCALE);
            au.x[1] = pkbf(q0.z * QSCALE, q0.w * QSCALE);
            au.x[2] = pkbf(q1.x * QSCALE, q1.y * QSCALE);
            au.x[3] = pkbf(q1.z * QSCALE, q1.w * QSCALE);
            aq[hi] = au.v;
        }
    }

    // ---------- fused MLP: only this block's 3 head-columns ----------
    if (t < NREL) {
        float x0 = (float)(t / 15 - 7);
        float x1 = (float)(t % 15 - 7);
        float h[PDIM], y[PDIM];
#pragma unroll
        for (int o = 0; o < PDIM; ++o)
            h[o] = x0 * wp[o] + x1 * wp[PDIM + o] + bp[o];
        ln_relu12(h, g1, be1, y);
#pragma unroll
        for (int o = 0; o < PDIM; ++o) {
            float a = b1[o];
#pragma unroll
            for (int i = 0; i < PDIM; ++i) a += y[i] * w1[i * PDIM + o];
            h[o] = a;
        }
        ln_relu12(h, g2, be2, y);
#pragma unroll
        for (int o = 0; o < PDIM; ++o) {
            float a = b2[o];
#pragma unroll
            for (int i = 0; i < PDIM; ++i) a += y[i] * w2[i * PDIM + o];
            h[o] = a;
        }
        ln_relu12(h, g3, be3, y);
#pragma unroll
        for (int hi = 0; hi < 3; ++hi) {
            int o = hg * 3 + hi;
            float a = b3[o];
#pragma unroll
            for (int i = 0; i < PDIM; ++i) a += y[i] * w3[i * NHEADS + o];
            pshf[t * 4 + hi] = a * LOG2E;
        }
    }
    __syncthreads();   // ks, vt, pshf visible; only barrier

    // ---------- S^T = mfma(K, Q): lane holds q-row lw ----------
    v4f acc[3][4];
#pragma unroll
    for (int ct = 0; ct < 4; ++ct) {
#pragma unroll
        for (int hi = 0; hi < 3; ++hi) {
            v4f z = {0.f, 0.f, 0.f, 0.f};
            v8s bfr = *(const v8s*)&ks[(ct * 16 + lw) * KS3 + hi * HD + lg * 8];
            acc[hi][ct] = __builtin_amdgcn_mfma_f32_16x16x32_bf16(bfr, aq[hi], z, 0, 0, 0);
        }
    }

    // ---------- bias + exp2 (swapped-layout indexing) ----------
    {
        const int q = rowbase + lw;
        const int base2 = ((q >> 3) + 7) * 15 + (q & 7) + 7
                        - ((lg >> 1) * 15 + (lg & 1) * 4);
#pragma unroll
        for (int ct = 0; ct < 4; ++ct)
#pragma unroll
            for (int r = 0; r < 4; ++r) {
                int idx = base2 - ct * 30 - r;
                const float4 bb = *(const float4*)&pshf[idx * 4];
                acc[0][ct][r] = ex2(acc[0][ct][r] + bb.x);
                acc[1][ct][r] = ex2(acc[1][ct][r] + bb.y);
                acc[2][ct][r] = ex2(acc[2][ct][r] + bb.z);
            }
    }

    // ---------- row-sum + normalize into PV A-fragments (in-register) ----------
    unsigned pa[3][2][4];
#pragma unroll
    for (int hi = 0; hi < 3; ++hi) {
        float s = 0.f;
#pragma unroll
        for (int ct = 0; ct < 4; ++ct)
#pragma unroll
            for (int r = 0; r < 4; ++r) s += acc[hi][ct][r];
        s += __shfl_xor(s, 16);
        s += __shfl_xor(s, 32);
        float rv = __builtin_amdgcn_rcpf(s);
#pragma unroll
        for (int kt = 0; kt < 2; ++kt) {
            pa[hi][kt][0] = pkbf(acc[hi][2*kt][0] * rv, acc[hi][2*kt][1] * rv);
            pa[hi][kt][1] = pkbf(acc[hi][2*kt][2] * rv, acc[hi][2*kt][3] * rv);
            pa[hi][kt][2] = pkbf(acc[hi][2*kt+1][0] * rv, acc[hi][2*kt+1][1] * rv);
            pa[hi][kt][3] = pkbf(acc[hi][2*kt+1][2] * rv, acc[hi][2*kt+1][3] * rv);
        }
    }

    // ---------- output offsets ----------
    size_t ooff[4];
#pragma unroll
    for (int r = 0; r < 4; ++r) {
        int n = rowbase + lg * 4 + r;
        ooff[r] = ((size_t)(b * IMG + bh * 8 + (n >> 3)) * IMG
                   + (bw * 8 + (n & 7))) * CDIM;
    }

    // ---------- O = P_norm V ----------
#pragma unroll
    for (int hi = 0; hi < 3; ++hi) {
        v4f acc2[2] = {};
#pragma unroll
        for (int kt = 0; kt < 2; ++kt) {
            v8s pav = *(const v8s*)&pa[hi][kt][0];
#pragma unroll
            for (int dt = 0; dt < 2; ++dt) {
                v8s vb = *(const v8s*)&vt[(hi * HD + dt * 16 + lw) * VTS
                                          + kt * 32 + lg * 8];
                acc2[dt] = __builtin_amdgcn_mfma_f32_16x16x32_bf16(pav, vb, acc2[dt], 0, 0, 0);
            }
        }
        const int h = hg * 3 + hi;
#pragma unroll
        for (int dt = 0; dt < 2; ++dt)
#pragma unroll
            for (int r = 0; r < 4; ++r)
                out[ooff[r] + h * HD + dt * 16 + lw] = acc2[dt][r];
    }
}

extern "C" void kernel_launch(void* const* d_in, const int* in_sizes, int n_in,
                              void* d_out, int out_size, void* d_ws, size_t ws_size,
                              hipStream_t stream) {
    const float* qkv = (const float*)d_in[0];
    win_attn_fused<<<NWIN * 2, 256, 0, stream>>>(
        qkv,
        (const float*)d_in[1], (const float*)d_in[2],
        (const float*)d_in[3], (const float*)d_in[4],
        (const float*)d_in[5], (const float*)d_in[6],
        (const float*)d_in[7], (const float*)d_in[8],
        (const float*)d_in[9], (const float*)d_in[10],
        (const float*)d_in[11], (const float*)d_in[12],
        (const float*)d_in[13], (const float*)d_in[14],
        (float*)d_out);
}